// Round 3
// baseline (1917.279 us; speedup 1.0000x reference)
//
#include <hip/hip_runtime.h>
#include <math.h>

#define LYR 24
#define TT  2048
#define DD  512
#define HH  16
#define VV  1025
#define TYY 512
#define FFD 2048
#define DHH 32

// ---------------- wave helpers (wave64) ----------------
__device__ __forceinline__ float wsum(float v){
#pragma unroll
  for (int m = 32; m > 0; m >>= 1) v += __shfl_xor(v, m, 64);
  return v;
}
__device__ __forceinline__ float wmax(float v){
#pragma unroll
  for (int m = 32; m > 0; m >>= 1) v = fmaxf(v, __shfl_xor(v, m, 64));
  return v;
}

// ---------------- A: qkv = x @ qkv_w (+redundant LN of pre2+ff2p) ----------------
// grid 192 = 24 colgroups x 8 rowchunks, block 64
__global__ __launch_bounds__(64) void k_qkv(
    const float* __restrict__ w,        // qkv_w + l*D*3D
    const float* __restrict__ pre2,     // ln1out + ff2_b base
    const float* __restrict__ ff2p,     // 32 x 512 deterministic partials
    const float* __restrict__ g2p, const float* __restrict__ b2p,  // layer l-1 ln2
    const float* __restrict__ tok_emb, const int* __restrict__ y,
    const float* __restrict__ alpha,
    float* __restrict__ qkvp, float* __restrict__ xbuf, int layer)
{
  int cg = blockIdx.x % 24, rc = blockIdx.x / 24;
  int lane = threadIdx.x;
  int r0 = rc * 64;
  __shared__ float xs[64];
  __shared__ float p2s[DD];

  if (layer == 0){
    int r = r0 + lane;
    int tok = y[TYY - 1];
    float e = tok_emb[(size_t)tok * DD + r];
    int i = r >> 1;
    float dv = expf((float)(2 * i) * -0.017988946039016f); // -ln(10000)/512
    float ang = 512.0f * dv;                                // pos = TY = 512
    float pv = (r & 1) ? cosf(ang) : sinf(ang);
    xs[lane] = e + alpha[0] * pv;
  } else {
    float loc[8]; float s = 0.f;
#pragma unroll
    for (int kk = 0; kk < 8; kk++){
      int d = lane + 64*kk;
      float v = pre2[d];
#pragma unroll 4
      for (int i = 0; i < 32; i++) v += ff2p[i*DD + d];   // fixed order: deterministic
      loc[kk] = v; s += v;
    }
    float mu = wsum(s) * (1.0f/512.0f);
    float vs = 0.f;
#pragma unroll
    for (int kk = 0; kk < 8; kk++){ float d = loc[kk]-mu; vs += d*d; }
    float var = wsum(vs) * (1.0f/512.0f);
    float rstd = 1.0f / sqrtf(var + 1e-5f);
#pragma unroll
    for (int kk = 0; kk < 8; kk++) p2s[lane + 64*kk] = loc[kk];
    __syncthreads();
    xs[lane] = (p2s[r0+lane] - mu) * rstd * g2p[r0+lane] + b2p[r0+lane];
  }
  if (cg == 0) xbuf[r0 + lane] = xs[lane];
  __syncthreads();

  int c = cg * 64 + lane;
  float acc = 0.f;
#pragma unroll 4
  for (int j = 0; j < 64; j++) acc += xs[j] * w[(size_t)(r0+j) * 1536 + c];
  qkvp[rc * 1536 + c] = acc;
}

// ---------------- B: attention partials (flash-style chunks) ----------------
// grid 272 = 16 heads x 17 chunks (16 cache chunks of 128 + 1 new-token), block 128
__global__ __launch_bounds__(128) void k_attn(
    const float* __restrict__ kc, const float* __restrict__ vc,
    const float* __restrict__ qkvp, const float* __restrict__ qkv_b,
    float* __restrict__ attp, float* __restrict__ kout, float* __restrict__ vout, int l)
{
  int h = blockIdx.x / 17, c = blockIdx.x % 17;
  int tid = threadIdx.x;
  __shared__ float qs[DHH];
  __shared__ float sh[128];
  __shared__ float ps[128];
  __shared__ float pv4[4][DHH];
  const float* bias = qkv_b + (size_t)l * 1536;

  if (tid < DHH){
    float q = bias[h*DHH + tid];
    for (int r = 0; r < 8; r++) q += qkvp[r*1536 + h*DHH + tid];
    qs[tid] = q;
  }
  __syncthreads();
  const float inv = 0.17677669529663687f; // 1/sqrt(32)
  float* ap = attp + (size_t)(h*17 + c) * 34;

  if (c < 16){
    int t = c * 128 + tid;
    const float* krow = kc + ((size_t)l*TT + t) * DD + h*DHH;
    const float4* k4 = reinterpret_cast<const float4*>(krow);
    float s = 0.f;
#pragma unroll
    for (int j = 0; j < 8; j++){
      float4 kv = k4[j];
      s += qs[4*j+0]*kv.x + qs[4*j+1]*kv.y + qs[4*j+2]*kv.z + qs[4*j+3]*kv.w;
    }
    s *= inv;
    sh[tid] = s; __syncthreads();
    for (int off = 64; off > 0; off >>= 1){ if (tid < off) sh[tid] = fmaxf(sh[tid], sh[tid+off]); __syncthreads(); }
    float m = sh[0];
    __syncthreads();
    float p = expf(s - m);
    ps[tid] = p;
    sh[tid] = p; __syncthreads();
    for (int off = 64; off > 0; off >>= 1){ if (tid < off) sh[tid] += sh[tid+off]; __syncthreads(); }
    float lsum = sh[0];
    int d = tid & 31, tg = tid >> 5;
    const float* vb = vc + ((size_t)l*TT + c*128 + tg*32) * DD + h*DHH + d;
    float av = 0.f;
#pragma unroll 4
    for (int j = 0; j < 32; j++) av += ps[tg*32 + j] * vb[(size_t)j * DD];
    pv4[tg][d] = av;
    __syncthreads();
    if (tid < DHH) ap[2+tid] = pv4[0][tid] + pv4[1][tid] + pv4[2][tid] + pv4[3][tid];
    if (tid == 0){ ap[0] = m; ap[1] = lsum; }
  } else {
    float vn = 0.f;
    if (tid < DHH){
      float kn = bias[DD + h*DHH + tid];
      vn = bias[2*DD + h*DHH + tid];
      for (int r = 0; r < 8; r++){
        kn += qkvp[r*1536 + DD  + h*DHH + tid];
        vn += qkvp[r*1536 + 2*DD + h*DHH + tid];
      }
      sh[tid] = kn;
      kout[(size_t)l*DD + h*DHH + tid] = kn;
      vout[(size_t)l*DD + h*DHH + tid] = vn;
    }
    __syncthreads();
    if (tid < DHH){
      float prod = qs[tid] * sh[tid];
#pragma unroll
      for (int mm = 16; mm > 0; mm >>= 1) prod += __shfl_xor(prod, mm, 64);
      float s = prod * inv;
      ap[2+tid] = vn;
      if (tid == 0){ ap[0] = s; ap[1] = 1.0f; }
    }
  }
}

// ---------------- C: combine attn partials per head + out-proj ----------------
// grid 128 = 16 heads x 8 colgroups, block 64
__global__ __launch_bounds__(64) void k_outproj(
    const float* __restrict__ attp, const float* __restrict__ ow, float* __restrict__ outp)
{
  int cg = blockIdx.x % 8, h = blockIdx.x / 8;
  int lane = threadIdx.x;
  __shared__ float os[DHH];
  const float* ab = attp + (size_t)h * 17 * 34;
  float mv = (lane < 17) ? ab[lane*34] : -INFINITY;
  float m = wmax(mv);
  float lw = (lane < 17) ? ab[lane*34+1] * expf(ab[lane*34] - m) : 0.f;
  float lg = wsum(lw);
  if (lane < DHH){
    float od = 0.f;
    for (int i = 0; i < 17; i++) od += expf(ab[i*34] - m) * ab[i*34 + 2 + lane];
    os[lane] = od / lg;
  }
  __syncthreads();
  int cc = cg * 64 + lane;
  float acc = 0.f;
#pragma unroll 4
  for (int d = 0; d < DHH; d++) acc += os[d] * ow[(size_t)(h*DHH + d) * DD + cc];
  outp[h * DD + cc] = acc;
}

// ---------------- D: pre1 combine + LN1 + ff1 partial (+pre2 base init) ----------------
// grid 256 = 32 colgroups x 8 rowchunks, block 64
__global__ __launch_bounds__(64) void k_ff1(
    const float* __restrict__ outp, const float* __restrict__ xbuf,
    const float* __restrict__ ob, const float* __restrict__ g1, const float* __restrict__ b1,
    const float* __restrict__ w1, const float* __restrict__ b2ff,
    float* __restrict__ ffp, float* __restrict__ pre2)
{
  int cg = blockIdx.x % 32, rc = blockIdx.x / 32;
  int lane = threadIdx.x;
  int r0 = rc * 64;
  __shared__ float p1s[DD];
  __shared__ float x1s[64];
  float loc[8]; float s = 0.f;
#pragma unroll
  for (int k2 = 0; k2 < 8; k2++){
    int d = lane*8 + k2;
    float v = xbuf[d] + ob[d];
    for (int hh = 0; hh < 16; hh++) v += outp[hh*DD + d];
    loc[k2] = v; s += v;
  }
  float mu = wsum(s) * (1.0f/512.0f);
  float vs = 0.f;
#pragma unroll
  for (int k2 = 0; k2 < 8; k2++){ float d = loc[k2]-mu; vs += d*d; }
  float var = wsum(vs) * (1.0f/512.0f);
  float rstd = 1.0f / sqrtf(var + 1e-5f);
#pragma unroll
  for (int k2 = 0; k2 < 8; k2++) p1s[lane*8+k2] = loc[k2];
  __syncthreads();
  x1s[lane] = (p1s[r0+lane] - mu) * rstd * g1[r0+lane] + b1[r0+lane];
  if (cg == 31) pre2[r0+lane] = x1s[lane] + b2ff[r0+lane];  // pre2 base = ln1out + ff2_b
  __syncthreads();
  int c = cg * 64 + lane;
  float acc = 0.f;
#pragma unroll 4
  for (int j = 0; j < 64; j++) acc += x1s[j] * w1[(size_t)(r0+j) * FFD + c];
  ffp[rc * FFD + c] = acc;
}

// ---------------- E: relu(ff) @ ff2_w -> deterministic partials ff2p ----------------
// grid 256 = 8 colgroups x 32 rowchunks, block 64
__global__ __launch_bounds__(64) void k_ff2(
    const float* __restrict__ ffp, const float* __restrict__ b1f,
    const float* __restrict__ w2, float* __restrict__ ff2p)
{
  int cg = blockIdx.x % 8, rc = blockIdx.x / 8;
  int lane = threadIdx.x;
  int f0 = rc * 64;
  __shared__ float ffs[64];
  float v = b1f[f0 + lane];
#pragma unroll
  for (int i = 0; i < 8; i++) v += ffp[i*FFD + f0 + lane];
  ffs[lane] = fmaxf(v, 0.f);
  __syncthreads();
  int c = cg * 64 + lane;
  float acc = 0.f;
#pragma unroll 4
  for (int j = 0; j < 64; j++) acc += ffs[j] * w2[(size_t)(f0+j) * DD + c];
  ff2p[rc * DD + c] = acc;   // no atomics: folded in fixed order by consumers
}

// ---------------- F: final LN (pre2+ff2p) + logits partials ----------------
// grid 136 = 17 colgroups x 8 rowchunks, block 64
__global__ __launch_bounds__(64) void k_pred(
    const float* __restrict__ pre2, const float* __restrict__ ff2p,
    const float* __restrict__ g2, const float* __restrict__ b2,
    const float* __restrict__ pw, float* __restrict__ logp)
{
  int cg = blockIdx.x % 17, rc = blockIdx.x / 17;
  int lane = threadIdx.x;
  int r0 = rc * 64;
  __shared__ float p2s[DD];
  __shared__ float xs[64];
  float loc[8]; float s = 0.f;
#pragma unroll
  for (int kk = 0; kk < 8; kk++){
    int d = lane + 64*kk;
    float v = pre2[d];
#pragma unroll 4
    for (int i = 0; i < 32; i++) v += ff2p[i*DD + d];
    loc[kk] = v; s += v;
  }
  float mu = wsum(s) * (1.0f/512.0f);
  float vs = 0.f;
#pragma unroll
  for (int kk = 0; kk < 8; kk++){ float d = loc[kk]-mu; vs += d*d; }
  float var = wsum(vs) * (1.0f/512.0f);
  float rstd = 1.0f / sqrtf(var + 1e-5f);
#pragma unroll
  for (int kk = 0; kk < 8; kk++) p2s[lane + 64*kk] = loc[kk];
  __syncthreads();
  xs[lane] = (p2s[r0+lane] - mu) * rstd * g2[r0+lane] + b2[r0+lane];
  __syncthreads();
  int c = cg * 64 + lane;
  if (c < VV){
    float acc = 0.f;
#pragma unroll 4
    for (int j = 0; j < 64; j++) acc += xs[j] * pw[(size_t)(r0+j) * VV + c];
    logp[rc * VV + c] = acc;
  }
}

// ---------------- sampling helpers ----------------
__device__ __forceinline__ unsigned rotl32(unsigned x, int r){ return (x << r) | (x >> (32 - r)); }

// jax.random.normal(key(42), (1025,)) element v — PARTITIONABLE threefry
// (jax_threefry_partitionable=True default since jax 0.4.36):
//   per element: counter (x0,x1) = (counts_hi=0, counts_lo=v), key (0,42)
//   bits = out0 ^ out1  (32-bit fold)
// Plan B if still wrong: (x0,x1)=(v,0); Plan C: bits=out0 (no fold).
__device__ float noise_at(int v){
  const unsigned k0 = 0u, k1 = 42u;
  const unsigned k2 = k0 ^ k1 ^ 0x1BD11BDAu;
  unsigned ks[3] = {k0, k1, k2};
  unsigned x0 = 0u + ks[0];             // counts_hi = 0
  unsigned x1 = (unsigned)v + ks[1];    // counts_lo = v
  const int rot[8] = {13, 15, 26, 6, 17, 29, 16, 24};
#pragma unroll
  for (int i = 0; i < 5; i++){
    const int* rr = (i % 2 == 0) ? rot : rot + 4;
#pragma unroll
    for (int q = 0; q < 4; q++){ x0 += x1; x1 = rotl32(x1, rr[q]); x1 ^= x0; }
    x0 += ks[(i+1)%3]; x1 += ks[(i+2)%3] + (unsigned)(i+1);
  }
  unsigned bits = x0 ^ x1;
  unsigned fb = (bits >> 9) | 0x3f800000u;
  float f = __uint_as_float(fb) - 1.0f;
  const float lo = -0.99999994f;          // nextafter(-1,0) in f32
  float u = f * 2.0f + lo;                // (hi-lo) rounds to 2.0f (tie-to-even)
  u = fmaxf(lo, u);
  // XLA ErfInv f32 polynomial (Giles)
  float w = -log1pf(-u * u);
  float p;
  if (w < 5.0f){
    w = w - 2.5f;
    p = 2.81022636e-08f;
    p = fmaf(p, w, 3.43273939e-07f);
    p = fmaf(p, w, -3.5233877e-06f);
    p = fmaf(p, w, -4.39150654e-06f);
    p = fmaf(p, w, 0.00021858087f);
    p = fmaf(p, w, -0.00125372503f);
    p = fmaf(p, w, -0.00417768164f);
    p = fmaf(p, w, 0.246640727f);
    p = fmaf(p, w, 1.50140941f);
  } else {
    w = sqrtf(w) - 3.0f;
    p = -0.000200214257f;
    p = fmaf(p, w, 0.000100950558f);
    p = fmaf(p, w, 0.00134934322f);
    p = fmaf(p, w, -0.00367342844f);
    p = fmaf(p, w, 0.00573950773f);
    p = fmaf(p, w, -0.0076224613f);
    p = fmaf(p, w, 0.00943887047f);
    p = fmaf(p, w, 1.00167406f);
    p = fmaf(p, w, 2.83297682f);
  }
  return 1.41421354f * (p * u);
}

// ---------------- G: logits combine + penalty + top-15 + softmax + sample ----------------
// grid 1, block 256
__global__ __launch_bounds__(256) void k_final(
    const float* __restrict__ logp, const int* __restrict__ y, float* __restrict__ out)
{
  __shared__ float lg[VV];
  __shared__ int   mark[VV];
  __shared__ float wk[VV];
  __shared__ float red[256];
  __shared__ int   redi[256];
  __shared__ float vals15[15];
  __shared__ int   remidx;
  int tid = threadIdx.x;

  for (int v = tid; v < VV; v += 256){
    float s = 0.f;
    for (int r = 0; r < 8; r++) s += logp[r*VV + v];
    lg[v] = s; mark[v] = 0;
  }
  __syncthreads();
  for (int i = tid; i < TYY; i += 256) mark[y[i]] = 1;
  __syncthreads();
  for (int v = tid; v < VV; v += 256){
    if (mark[v]){ float s = lg[v]; lg[v] = (s < 0.f) ? s * 1.35f : s / 1.35f; }
    wk[v] = lg[v];
  }
  __syncthreads();

  // top-15 with multiplicity: 15 extraction rounds
  for (int it = 0; it < 15; it++){
    float lm = -INFINITY;
    for (int v = tid; v < VV; v += 256) lm = fmaxf(lm, wk[v]);
    red[tid] = lm; __syncthreads();
    for (int off = 128; off > 0; off >>= 1){
      if (tid < off) red[tid] = fmaxf(red[tid], red[tid+off]);
      __syncthreads();
    }
    float m = red[0];
    if (tid == 0) remidx = VV;
    __syncthreads();
    for (int v = tid; v < VV; v += 256) if (wk[v] == m) atomicMin(&remidx, v);
    __syncthreads();
    if (tid == 0){ wk[remidx] = -INFINITY; vals15[it] = m; }
    __syncthreads();
  }
  float thr = vals15[14], M = vals15[0];

  // softmax denominator over kept entries
  float zp = 0.f;
  for (int v = tid; v < VV; v += 256) if (lg[v] >= thr) zp += expf(lg[v] - M);
  red[tid] = zp; __syncthreads();
  for (int off = 128; off > 0; off >>= 1){
    if (tid < off) red[tid] += red[tid+off];
    __syncthreads();
  }
  float Z = red[0];
  __syncthreads();

  // probs + argmax(probs/noise) with first-index tiebreak
  float bv = -INFINITY; int bi = VV;
  for (int v = tid; v < VV; v += 256){
    bool kept = (lg[v] >= thr);
    float p = kept ? expf(lg[v] - M) / Z : 0.0f;
    out[v] = p;
    float nz = noise_at(v);
    float val = p / nz;
    if (val > bv){ bv = val; bi = v; }
  }
  red[tid] = bv; redi[tid] = bi; __syncthreads();
  for (int off = 128; off > 0; off >>= 1){
    if (tid < off){
      float ov = red[tid+off]; int oi = redi[tid+off];
      if (ov > red[tid] || (ov == red[tid] && oi < redi[tid])){ red[tid] = ov; redi[tid] = oi; }
    }
    __syncthreads();
  }
  if (tid == 0) out[VV] = (float)redi[0];
}

// ---------------- host ----------------
extern "C" void kernel_launch(void* const* d_in, const int* in_sizes, int n_in,
                              void* d_out, int out_size, void* d_ws, size_t ws_size,
                              hipStream_t stream)
{
  const int*   y       = (const int*)d_in[0];
  const float* kc      = (const float*)d_in[1];
  const float* vc      = (const float*)d_in[2];
  // d_in[3] = y_emb: unused (only its appended last row matters)
  const float* tok_emb = (const float*)d_in[4];
  const float* alpha   = (const float*)d_in[5];
  const float* qkv_w   = (const float*)d_in[6];
  const float* qkv_b   = (const float*)d_in[7];
  const float* out_w   = (const float*)d_in[8];
  const float* out_b   = (const float*)d_in[9];
  const float* ln1_g   = (const float*)d_in[10];
  const float* ln1_b   = (const float*)d_in[11];
  const float* ff1_w   = (const float*)d_in[12];
  const float* ff1_b   = (const float*)d_in[13];
  const float* ff2_w   = (const float*)d_in[14];
  const float* ff2_b   = (const float*)d_in[15];
  const float* ln2_g   = (const float*)d_in[16];
  const float* ln2_b   = (const float*)d_in[17];
  const float* pred_w  = (const float*)d_in[18];

  float* ws   = (float*)d_ws;
  float* xbuf = ws;                  // 512
  float* qkvp = xbuf + 512;          // 8*1536
  float* attp = qkvp + 8*1536;       // 16*17*34
  float* outp = attp + 16*17*34;     // 16*512
  float* ffp  = outp + 16*512;       // 8*2048
  float* pre2 = ffp  + 8*2048;       // 512
  float* ff2p = pre2 + 512;          // 32*512
  float* logp = ff2p + 32*512;       // 8*1025

  float* out  = (float*)d_out;
  float* kout = out + VV + 1;        // k_new at 1026
  float* vout = kout + LYR*DD;       // v_new

  for (int l = 0; l < LYR; l++){
    const float* g2p = (l == 0) ? ln2_g : ln2_g + (size_t)(l-1)*DD;
    const float* b2p = (l == 0) ? ln2_b : ln2_b + (size_t)(l-1)*DD;
    k_qkv<<<192, 64, 0, stream>>>(qkv_w + (size_t)l*DD*3*DD, pre2, ff2p, g2p, b2p,
                                  tok_emb, y, alpha, qkvp, xbuf, l);
    k_attn<<<272, 128, 0, stream>>>(kc, vc, qkvp, qkv_b, attp, kout, vout, l);
    k_outproj<<<128, 64, 0, stream>>>(attp, out_w + (size_t)l*DD*DD, outp);
    k_ff1<<<256, 64, 0, stream>>>(outp, xbuf, out_b + (size_t)l*DD,
                                  ln1_g + (size_t)l*DD, ln1_b + (size_t)l*DD,
                                  ff1_w + (size_t)l*DD*FFD, ff2_b + (size_t)l*DD,
                                  ffp, pre2);
    k_ff2<<<256, 64, 0, stream>>>(ffp, ff1_b + (size_t)l*FFD,
                                  ff2_w + (size_t)l*FFD*DD, ff2p);
  }
  k_pred<<<136, 64, 0, stream>>>(pre2, ff2p, ln2_g + (size_t)23*DD, ln2_b + (size_t)23*DD,
                                 pred_w, logp);
  k_final<<<1, 256, 0, stream>>>(logp, y, out);
}